// Round 3
// baseline (861.629 us; speedup 1.0000x reference)
//
#include <hip/hip_runtime.h>
#include <math.h>

#define T_ 128
#define B_ 32
#define V_ 32000
#define E_ 32
#define H_ 16

// ws layout (floats):
//   xw         [2][T][B][H]   offset      0, 131072 floats
//   feats      [T][B][2H]     offset 131072, 131072 floats
//   stats_part [T*B][4]       offset 262144,  16384 floats
//   lse        [T*B]          offset 278528,   4096 floats

// Kernel 0: input contribution xw[dir][t][b][j] = b_ih[j] + emb[ix[t][b]] @ W[0:E, j]
__global__ __launch_bounds__(256) void xw_kernel(const int* __restrict__ ix,
                                                 const float* __restrict__ emb,
                                                 const float* __restrict__ W_lr,
                                                 const float* __restrict__ b_lr,
                                                 const float* __restrict__ W_rl,
                                                 const float* __restrict__ b_rl,
                                                 float* __restrict__ xw) {
    int idx = blockIdx.x * 256 + threadIdx.x;          // 131072 total
    int j = idx & 15;
    int b = (idx >> 4) & 31;
    int t = (idx >> 9) & 127;
    int dir = idx >> 16;
    const float* W    = dir ? W_rl : W_lr;
    const float* bias = dir ? b_rl : b_lr;
    int tok = ix[t * B_ + b];
    const float* er = emb + (long)tok * E_;
    float acc = bias[j];
#pragma unroll
    for (int e = 0; e < E_; ++e) acc += er[e] * W[e * H_ + j];
    xw[idx] = acc;
}

// Kernel 1: the two sequential scans. One block per direction, 512 threads = (b,j).
__global__ __launch_bounds__(512) void scan_kernel(const float* __restrict__ xw,
                                                   const float* __restrict__ W_lr,
                                                   const float* __restrict__ W_rl,
                                                   const float* __restrict__ h0p,
                                                   const float* __restrict__ mask_lr,
                                                   const float* __restrict__ mask_rl,
                                                   float* __restrict__ feats) {
    int dir = blockIdx.x;
    int tid = threadIdx.x;
    int b = tid >> 4, j = tid & 15;
    const float* W    = dir ? W_rl : W_lr;
    const float* mask = dir ? mask_rl : mask_lr;
    const float* xwd  = xw + dir * (T_ * B_ * H_);
    float Wh[16];
#pragma unroll
    for (int k = 0; k < 16; ++k) Wh[k] = W[(E_ + k) * H_ + j];
    __shared__ float hs[32][16];
    float h0j = h0p[j];
    hs[b][j] = h0j;
    if (dir == 0) feats[(0 * B_ + b) * 32 + j] = h0j;
    else          feats[((T_ - 1) * B_ + b) * 32 + 16 + j] = h0j;
    __syncthreads();
    for (int t = 0; t < T_; ++t) {
        int tt = dir ? (T_ - 1 - t) : t;   // token position consumed this step
        float acc = xwd[tt * (B_ * H_) + tid];
        const float4* h4 = (const float4*)(&hs[b][0]);
#pragma unroll
        for (int kk = 0; kk < 4; ++kk) {
            float4 hv = h4[kk];
            acc += hv.x * Wh[4 * kk] + hv.y * Wh[4 * kk + 1] +
                   hv.z * Wh[4 * kk + 2] + hv.w * Wh[4 * kk + 3];
        }
        float hn = tanhf(acc) * mask[tt * (B_ * H_) + tid];
        __syncthreads();
        hs[b][j] = hn;
        __syncthreads();
        if (t < T_ - 1) {
            int p = dir ? (T_ - 2 - t) : (t + 1);
            feats[(p * B_ + b) * 32 + dir * 16 + j] = hn;
        }
    }
}

// Kernel 2: per-row sum(exp(logit)). Reg-blocked GEMM structure:
// block = 256 threads = 4 waves; wave w owns rows rb*16 + w*4 .. +3 (fr[4][32] in regs);
// lane owns one column per 64-wide tile; 125 tiles cover an 8000-col segment.
// Per-thread regs: fr 128 + Wc 32 + acc 4 ~= 185 -> no spill, no LDS.
__global__ __launch_bounds__(256) void stats_kernel(const float* __restrict__ feats,
                                                    const float* __restrict__ W_ho,
                                                    const float* __restrict__ b_ho,
                                                    float* __restrict__ stats_part) {
    int rb = blockIdx.x;    // 0..255 (row tile of 16)
    int sg = blockIdx.y;    // 0..3  (V segment of 8000)
    int tid = threadIdx.x;
    int wv = tid >> 6, lane = tid & 63;
    int row0 = rb * 16 + wv * 4;
    float fr[4][32];
#pragma unroll
    for (int r = 0; r < 4; ++r)
#pragma unroll
        for (int k = 0; k < 32; ++k) fr[r][k] = feats[(row0 + r) * 32 + k];
    float acc[4] = {0.f, 0.f, 0.f, 0.f};
#pragma unroll 1
    for (int tile = 0; tile < 125; ++tile) {
        int c = sg * 8000 + tile * 64 + lane;   // < 32000 always
        float Wc[32];
#pragma unroll
        for (int k = 0; k < 32; ++k) Wc[k] = W_ho[k * V_ + c];
        float bc = b_ho[c];
#pragma unroll
        for (int r = 0; r < 4; ++r) {
            float s = bc;
#pragma unroll
            for (int k = 0; k < 32; ++k) s += fr[r][k] * Wc[k];
            acc[r] += __expf(s);   // |logit| <= 10.25 -> no max subtraction needed
        }
    }
#pragma unroll
    for (int r = 0; r < 4; ++r) {
        float v = acc[r];
        for (int off = 32; off > 0; off >>= 1) v += __shfl_down(v, off, 64);
        if (lane == 0) stats_part[(row0 + r) * 4 + sg] = v;
    }
}

// Kernel 2b: lse[row] = log(sum of 4 segment partials)
__global__ __launch_bounds__(256) void lse_kernel(const float* __restrict__ stats_part,
                                                  float* __restrict__ lse) {
    int r = blockIdx.x * 256 + threadIdx.x;
    if (r < T_ * B_) {
        float4 p = ((const float4*)stats_part)[r];
        lse[r] = __logf(p.x + p.y + p.z + p.w);
    }
}

// Kernel 3: recompute logits, write out = logit - lse. Same reg-blocked structure.
__global__ __launch_bounds__(256) void out_kernel(const float* __restrict__ feats,
                                                  const float* __restrict__ W_ho,
                                                  const float* __restrict__ b_ho,
                                                  const float* __restrict__ lse,
                                                  float* __restrict__ out) {
    int rb = blockIdx.x;    // 0..255 (row tile of 16)
    int sg = blockIdx.y;    // 0..3
    int tid = threadIdx.x;
    int wv = tid >> 6, lane = tid & 63;
    int row0 = rb * 16 + wv * 4;
    float fr[4][32];
    float ls[4];
#pragma unroll
    for (int r = 0; r < 4; ++r) {
        ls[r] = lse[row0 + r];
#pragma unroll
        for (int k = 0; k < 32; ++k) fr[r][k] = feats[(row0 + r) * 32 + k];
    }
#pragma unroll 1
    for (int tile = 0; tile < 125; ++tile) {
        int c = sg * 8000 + tile * 64 + lane;
        float Wc[32];
#pragma unroll
        for (int k = 0; k < 32; ++k) Wc[k] = W_ho[k * V_ + c];
        float bc = b_ho[c];
#pragma unroll
        for (int r = 0; r < 4; ++r) {
            float s = bc;
#pragma unroll
            for (int k = 0; k < 32; ++k) s += fr[r][k] * Wc[k];
            out[(long)(row0 + r) * V_ + c] = s - ls[r];
        }
    }
}

extern "C" void kernel_launch(void* const* d_in, const int* in_sizes, int n_in,
                              void* d_out, int out_size, void* d_ws, size_t ws_size,
                              hipStream_t stream) {
    const int*   ix      = (const int*)d_in[0];
    const float* emb     = (const float*)d_in[1];
    const float* W_lr    = (const float*)d_in[2];
    const float* b_lr    = (const float*)d_in[3];
    const float* W_rl    = (const float*)d_in[4];
    const float* b_rl    = (const float*)d_in[5];
    const float* W_ho    = (const float*)d_in[6];
    const float* b_ho    = (const float*)d_in[7];
    const float* h0      = (const float*)d_in[8];
    const float* mask_lr = (const float*)d_in[9];
    const float* mask_rl = (const float*)d_in[10];
    float* out = (float*)d_out;
    float* ws  = (float*)d_ws;

    float* xw         = ws;                 // 131072
    float* feats      = ws + 131072;        // 131072
    float* stats_part = ws + 262144;        //  16384
    float* lse        = ws + 278528;        //   4096

    xw_kernel<<<512, 256, 0, stream>>>(ix, emb, W_lr, b_lr, W_rl, b_rl, xw);
    scan_kernel<<<2, 512, 0, stream>>>(xw, W_lr, W_rl, h0, mask_lr, mask_rl, feats);
    stats_kernel<<<dim3(256, 4), 256, 0, stream>>>(feats, W_ho, b_ho, stats_part);
    lse_kernel<<<16, 256, 0, stream>>>(stats_part, lse);
    out_kernel<<<dim3(256, 4), 256, 0, stream>>>(feats, W_ho, b_ho, lse, out);
}

// Round 4
// 339.639 us; speedup vs baseline: 2.5369x; 2.5369x over previous
//
#include <hip/hip_runtime.h>
#include <hip/hip_bf16.h>
#include <math.h>

#define T_ 128
#define B_ 32
#define V_ 32000
#define E_ 32
#define H_ 16
#define NROW 4096       // T*B rows
#define NSEG 16         // column segments
#define SEGW 2000       // V/NSEG
#define NTILE 125       // SEGW/16

typedef __attribute__((ext_vector_type(8))) short short8;  // bf16x8 MFMA fragment
typedef __attribute__((ext_vector_type(4))) float f32x4;

// ws layout (float units):
//   xw         [2][T][B][H] f32      @ 0       (131072 floats)
//   featsB     [4096][32]   bf16     @ 131072  (65536 floats)
//   W_hoT      [32000][32]  bf16     @ 196608  (512000 floats)
//   stats_part [4096][16]   f32      @ 708608  (65536 floats)
//   lse        [4096]       f32      @ 774144  (4096 floats)

// Kernel 0: xw[dir][t][b][j] = b_ih[j] + emb[ix[t][b]] @ W[0:E, j]
__global__ __launch_bounds__(256) void xw_kernel(const int* __restrict__ ix,
                                                 const float* __restrict__ emb,
                                                 const float* __restrict__ W_lr,
                                                 const float* __restrict__ b_lr,
                                                 const float* __restrict__ W_rl,
                                                 const float* __restrict__ b_rl,
                                                 float* __restrict__ xw) {
    int idx = blockIdx.x * 256 + threadIdx.x;          // 131072 total
    int j = idx & 15;
    int b = (idx >> 4) & 31;
    int t = (idx >> 9) & 127;
    int dir = idx >> 16;
    const float* W    = dir ? W_rl : W_lr;
    const float* bias = dir ? b_rl : b_lr;
    int tok = ix[t * B_ + b];
    const float* er = emb + (long)tok * E_;
    float acc = bias[j];
#pragma unroll
    for (int e = 0; e < E_; ++e) acc += er[e] * W[e * H_ + j];
    xw[idx] = acc;
}

// Kernel 1: sequential scans; h kept f32 in LDS, feats written directly as bf16.
__global__ __launch_bounds__(512) void scan_kernel(const float* __restrict__ xw,
                                                   const float* __restrict__ W_lr,
                                                   const float* __restrict__ W_rl,
                                                   const float* __restrict__ h0p,
                                                   const float* __restrict__ mask_lr,
                                                   const float* __restrict__ mask_rl,
                                                   __hip_bfloat16* __restrict__ featsB) {
    int dir = blockIdx.x;
    int tid = threadIdx.x;
    int b = tid >> 4, j = tid & 15;
    const float* W    = dir ? W_rl : W_lr;
    const float* mask = dir ? mask_rl : mask_lr;
    const float* xwd  = xw + dir * (T_ * B_ * H_);
    float Wh[16];
#pragma unroll
    for (int k = 0; k < 16; ++k) Wh[k] = W[(E_ + k) * H_ + j];
    __shared__ float hs[32][16];
    float h0j = h0p[j];
    hs[b][j] = h0j;
    if (dir == 0) featsB[(0 * B_ + b) * 32 + j] = __float2bfloat16(h0j);
    else          featsB[((T_ - 1) * B_ + b) * 32 + 16 + j] = __float2bfloat16(h0j);
    __syncthreads();
    for (int t = 0; t < T_; ++t) {
        int tt = dir ? (T_ - 1 - t) : t;
        float acc = xwd[tt * (B_ * H_) + tid];
        const float4* h4 = (const float4*)(&hs[b][0]);
#pragma unroll
        for (int kk = 0; kk < 4; ++kk) {
            float4 hv = h4[kk];
            acc += hv.x * Wh[4 * kk] + hv.y * Wh[4 * kk + 1] +
                   hv.z * Wh[4 * kk + 2] + hv.w * Wh[4 * kk + 3];
        }
        float hn = tanhf(acc) * mask[tt * (B_ * H_) + tid];
        __syncthreads();
        hs[b][j] = hn;
        __syncthreads();
        if (t < T_ - 1) {
            int p = dir ? (T_ - 2 - t) : (t + 1);
            featsB[(p * B_ + b) * 32 + dir * 16 + j] = __float2bfloat16(hn);
        }
    }
}

// Kernel 1b: W_hoT[c][k] = bf16(W_ho[k][c]); reads coalesced per k, writes 64B/thread.
__global__ __launch_bounds__(256) void wt_kernel(const float* __restrict__ W_ho,
                                                 __hip_bfloat16* __restrict__ W_hoT) {
    int c = blockIdx.x * 256 + threadIdx.x;    // 125 blocks -> 32000 exactly
    __hip_bfloat16 tmp[32];
#pragma unroll
    for (int k = 0; k < 32; ++k) tmp[k] = __float2bfloat16(W_ho[k * V_ + c]);
    short8* dst = (short8*)(W_hoT + c * 32);
    const short8* src = (const short8*)tmp;
#pragma unroll
    for (int q = 0; q < 4; ++q) dst[q] = src[q];
}

// MFMA fragment addressing (16x16x32, operand-swapped: A = W-tile [16 cols x 32 k],
// B = feats [32 k x 16 rows]):
//   lane L: p = L & 15 (A-row / B-col), kb = (L >> 4) * 8 (k base, 8 consecutive)
//   D[i][j]: lane (j | (i/4)<<4... ) -> lane holds i = (L>>4)*4 + reg (here: col),
//            j = L&15 (here: row).  [C/D layout per m89, dtype-independent]

// Kernel 2: per-row sum(exp(logit)). One wave = 16 rows x one 2000-col segment.
__global__ __launch_bounds__(256) void stats_kernel(const __hip_bfloat16* __restrict__ featsB,
                                                    const __hip_bfloat16* __restrict__ W_hoT,
                                                    const float* __restrict__ b_ho,
                                                    float* __restrict__ stats_part) {
    int wid = blockIdx.x * 4 + (threadIdx.x >> 6);   // 0..4095
    int lane = threadIdx.x & 63;
    int rt = wid >> 4;          // row tile 0..255
    int seg = wid & 15;         // segment 0..15
    int row0 = rt * 16;
    int p = lane & 15, kb = (lane >> 4) * 8;
    short8 bfrag = *(const short8*)((const short*)featsB + (row0 + p) * 32 + kb); // feats as B
    float racc = 0.f;           // running sum for row row0+p (this lane-group's col quad)
    int cbase = seg * SEGW;
#pragma unroll 1
    for (int tile = 0; tile < NTILE; ++tile) {
        int c0 = cbase + tile * 16;
        short8 afrag = *(const short8*)((const short*)W_hoT + (c0 + p) * 32 + kb); // W as A
        f32x4 b4 = *(const f32x4*)(b_ho + c0 + ((lane >> 4) << 2));
        f32x4 lg = __builtin_amdgcn_mfma_f32_16x16x32_bf16(
            afrag, bfrag, (f32x4){0.f, 0.f, 0.f, 0.f}, 0, 0, 0);
        // lane holds logits for row (row0+p), cols c0 + (lane>>4)*4 + r
        racc += __expf(lg[0] + b4[0]) + __expf(lg[1] + b4[1]) +
                __expf(lg[2] + b4[2]) + __expf(lg[3] + b4[3]);
    }
    // reduce across the 4 col-quad groups (lanes p, p+16, p+32, p+48)
    racc += __shfl_xor(racc, 16, 64);
    racc += __shfl_xor(racc, 32, 64);
    if (lane < 16) stats_part[(row0 + lane) * NSEG + seg] = racc;
}

// Kernel 2b: lse[row] = log(sum of 16 segment partials)
__global__ __launch_bounds__(256) void lse_kernel(const float* __restrict__ stats_part,
                                                  float* __restrict__ lse) {
    int r = blockIdx.x * 256 + threadIdx.x;   // 16 blocks -> 4096
    const f32x4* p4 = (const f32x4*)(stats_part + r * NSEG);
    f32x4 a = p4[0], b = p4[1], c = p4[2], d = p4[3];
    float s = (a[0]+a[1]+a[2]+a[3]) + (b[0]+b[1]+b[2]+b[3]) +
              (c[0]+c[1]+c[2]+c[3]) + (d[0]+d[1]+d[2]+d[3]);
    lse[r] = __logf(s);
}

// Kernel 3: out = logit - lse, recomputed via MFMA; f32x4 stores (4 consecutive cols).
__global__ __launch_bounds__(256) void out_kernel(const __hip_bfloat16* __restrict__ featsB,
                                                  const __hip_bfloat16* __restrict__ W_hoT,
                                                  const float* __restrict__ b_ho,
                                                  const float* __restrict__ lse,
                                                  float* __restrict__ out) {
    int wid = blockIdx.x * 4 + (threadIdx.x >> 6);
    int lane = threadIdx.x & 63;
    int rt = wid >> 4;
    int seg = wid & 15;
    int row0 = rt * 16;
    int p = lane & 15, kb = (lane >> 4) * 8;
    short8 bfrag = *(const short8*)((const short*)featsB + (row0 + p) * 32 + kb);
    float ls = lse[row0 + p];   // this lane's single output row
    int cbase = seg * SEGW;
    float* orow = out + (long)(row0 + p) * V_;
#pragma unroll 1
    for (int tile = 0; tile < NTILE; ++tile) {
        int c0 = cbase + tile * 16;
        short8 afrag = *(const short8*)((const short*)W_hoT + (c0 + p) * 32 + kb);
        f32x4 b4 = *(const f32x4*)(b_ho + c0 + ((lane >> 4) << 2));
        f32x4 lg = __builtin_amdgcn_mfma_f32_16x16x32_bf16(
            afrag, bfrag, (f32x4){0.f, 0.f, 0.f, 0.f}, 0, 0, 0);
        f32x4 o;
        o[0] = lg[0] + b4[0] - ls;
        o[1] = lg[1] + b4[1] - ls;
        o[2] = lg[2] + b4[2] - ls;
        o[3] = lg[3] + b4[3] - ls;
        *(f32x4*)(orow + c0 + ((lane >> 4) << 2)) = o;
    }
}

extern "C" void kernel_launch(void* const* d_in, const int* in_sizes, int n_in,
                              void* d_out, int out_size, void* d_ws, size_t ws_size,
                              hipStream_t stream) {
    const int*   ix      = (const int*)d_in[0];
    const float* emb     = (const float*)d_in[1];
    const float* W_lr    = (const float*)d_in[2];
    const float* b_lr    = (const float*)d_in[3];
    const float* W_rl    = (const float*)d_in[4];
    const float* b_rl    = (const float*)d_in[5];
    const float* W_ho    = (const float*)d_in[6];
    const float* b_ho    = (const float*)d_in[7];
    const float* h0      = (const float*)d_in[8];
    const float* mask_lr = (const float*)d_in[9];
    const float* mask_rl = (const float*)d_in[10];
    float* out = (float*)d_out;
    float* ws  = (float*)d_ws;

    float*           xw         = ws;                                   // 131072 f32
    __hip_bfloat16*  featsB     = (__hip_bfloat16*)(ws + 131072);       // 65536 f32-equiv
    __hip_bfloat16*  W_hoT      = (__hip_bfloat16*)(ws + 196608);       // 512000 f32-equiv
    float*           stats_part = ws + 708608;                          // 65536 f32
    float*           lse        = ws + 774144;                          // 4096 f32

    xw_kernel<<<512, 256, 0, stream>>>(ix, emb, W_lr, b_lr, W_rl, b_rl, xw);
    wt_kernel<<<125, 256, 0, stream>>>(W_ho, W_hoT);
    scan_kernel<<<2, 512, 0, stream>>>(xw, W_lr, W_rl, h0, mask_lr, mask_rl, featsB);
    stats_kernel<<<1024, 256, 0, stream>>>(featsB, W_hoT, b_ho, stats_part);
    lse_kernel<<<16, 256, 0, stream>>>(stats_part, lse);
    out_kernel<<<1024, 256, 0, stream>>>(featsB, W_hoT, b_ho, lse, out);
}

// Round 5
// 297.812 us; speedup vs baseline: 2.8932x; 1.1404x over previous
//
#include <hip/hip_runtime.h>
#include <hip/hip_bf16.h>
#include <math.h>

#define T_ 128
#define B_ 32
#define V_ 32000
#define E_ 32
#define H_ 16
#define NSEG 20         // column segments
#define SEGW 1600       // V/NSEG
#define NIT 50          // SEGW/32 (two 16-col MFMA tiles per iteration)

typedef __attribute__((ext_vector_type(8))) short short8;  // bf16x8 MFMA fragment
typedef __attribute__((ext_vector_type(4))) float f32x4;

// ws layout (float units):
//   xw         [2][T][B][H] f32      @ 0       (131072)
//   featsB     [4096][32]   bf16     @ 131072  (65536)
//   W_hoT      [32000][32]  bf16     @ 196608  (512000)
//   stats_part [4096][20]   f32      @ 708608  (81920)
//   lse        [4096]       f32      @ 790528  (4096)   -> 794624 floats ~3.2 MB

// Kernel 0: xw[dir][t][b][j] = b_ih[j] + emb[ix[t][b]] @ W[0:E, j]
__global__ __launch_bounds__(256) void xw_kernel(const int* __restrict__ ix,
                                                 const float* __restrict__ emb,
                                                 const float* __restrict__ W_lr,
                                                 const float* __restrict__ b_lr,
                                                 const float* __restrict__ W_rl,
                                                 const float* __restrict__ b_rl,
                                                 float* __restrict__ xw) {
    int idx = blockIdx.x * 256 + threadIdx.x;          // 131072 total
    int j = idx & 15;
    int b = (idx >> 4) & 31;
    int t = (idx >> 9) & 127;
    int dir = idx >> 16;
    const float* W    = dir ? W_rl : W_lr;
    const float* bias = dir ? b_rl : b_lr;
    int tok = ix[t * B_ + b];
    const float* er = emb + (long)tok * E_;
    float acc = bias[j];
#pragma unroll
    for (int e = 0; e < E_; ++e) acc += er[e] * W[e * H_ + j];
    xw[idx] = acc;
}

// Kernel 1: sequential scans, barrier-free. Thread (b,j); the 16 threads of each b
// live in one wave (base = lane&48), so h-exchange is pure __shfl. xw/mask are
// double-buffered in 4-step chunks to hide load latency.
__global__ __launch_bounds__(512) void scan_kernel(const float* __restrict__ xw,
                                                   const float* __restrict__ W_lr,
                                                   const float* __restrict__ W_rl,
                                                   const float* __restrict__ h0p,
                                                   const float* __restrict__ mask_lr,
                                                   const float* __restrict__ mask_rl,
                                                   __hip_bfloat16* __restrict__ featsB) {
    int dir = blockIdx.x;
    int tid = threadIdx.x;
    int lane = tid & 63;
    int j = lane & 15;
    int b = tid >> 4;
    int base = lane & 48;
    const float* W    = dir ? W_rl : W_lr;
    const float* mask = dir ? mask_rl : mask_lr;
    const float* xwd  = xw + dir * (T_ * B_ * H_);
    float Wh[16];
#pragma unroll
    for (int k = 0; k < 16; ++k) Wh[k] = W[(E_ + k) * H_ + j];
    float h = h0p[j];
    if (dir == 0) featsB[(0 * B_ + b) * 32 + j] = __float2bfloat16(h);
    else          featsB[((T_ - 1) * B_ + b) * 32 + 16 + j] = __float2bfloat16(h);

    float x0[4], m0[4], x1[4], m1[4];
#define LOADCH(XB, MB, CH)                                                 \
    _Pragma("unroll")                                                      \
    for (int u = 0; u < 4; ++u) {                                          \
        int t = (CH) * 4 + u;                                              \
        int tt = dir ? (T_ - 1 - t) : t;                                   \
        XB[u] = xwd[tt * (B_ * H_) + tid];                                 \
        MB[u] = mask[tt * (B_ * H_) + tid];                                \
    }
#define STEPS(XB, MB, CH)                                                  \
    _Pragma("unroll")                                                      \
    for (int u = 0; u < 4; ++u) {                                          \
        int t = (CH) * 4 + u;                                              \
        float a0 = XB[u], a1 = 0.f, a2 = 0.f, a3 = 0.f;                    \
        _Pragma("unroll")                                                  \
        for (int k = 0; k < 16; k += 4) {                                  \
            a0 += __shfl(h, base + k,     64) * Wh[k];                     \
            a1 += __shfl(h, base + k + 1, 64) * Wh[k + 1];                 \
            a2 += __shfl(h, base + k + 2, 64) * Wh[k + 2];                 \
            a3 += __shfl(h, base + k + 3, 64) * Wh[k + 3];                 \
        }                                                                  \
        float hn = tanhf((a0 + a1) + (a2 + a3)) * MB[u];                   \
        h = hn;                                                            \
        int p = dir ? (T_ - 2 - t) : (t + 1);                              \
        if (p >= 0 && p < T_)                                              \
            featsB[(p * B_ + b) * 32 + dir * 16 + j] = __float2bfloat16(hn); \
    }
    LOADCH(x0, m0, 0)
#pragma unroll 1
    for (int c = 0; c < 32; c += 2) {
        if (c + 1 < 32) { LOADCH(x1, m1, c + 1) }
        STEPS(x0, m0, c)
        if (c + 2 < 32) { LOADCH(x0, m0, c + 2) }
        STEPS(x1, m1, c + 1)
    }
#undef LOADCH
#undef STEPS
}

// Kernel 1b: W_hoT[c][k] = bf16(W_ho[k][c])
__global__ __launch_bounds__(256) void wt_kernel(const float* __restrict__ W_ho,
                                                 __hip_bfloat16* __restrict__ W_hoT) {
    int c = blockIdx.x * 256 + threadIdx.x;    // 125 blocks -> 32000 exactly
    __hip_bfloat16 tmp[32];
#pragma unroll
    for (int k = 0; k < 32; ++k) tmp[k] = __float2bfloat16(W_ho[k * V_ + c]);
    short8* dst = (short8*)(W_hoT + c * 32);
    const short8* src = (const short8*)tmp;
#pragma unroll
    for (int q = 0; q < 4; ++q) dst[q] = src[q];
}

// MFMA (16x16x32, operand-swapped: A = W-tile [16 cols x 32 k], B = feats):
//   lane L: p = L&15, kb = (L>>4)*8; D: lane holds row (L&15), cols c0+(L>>4)*4+{0..3}

// Kernel 2: per-row sum(exp(logit)). Wave = 16 rows x one seg; 50 iters x 32 cols,
// 2 MFMAs/iter, afrags prefetched one iteration ahead.
__global__ __launch_bounds__(256) void stats_kernel(const __hip_bfloat16* __restrict__ featsB,
                                                    const __hip_bfloat16* __restrict__ W_hoT,
                                                    const float* __restrict__ b_ho,
                                                    float* __restrict__ stats_part) {
    int wv = threadIdx.x >> 6, lane = threadIdx.x & 63;
    int rt = blockIdx.x * 4 + wv;        // 0..255
    int seg = blockIdx.y;                // 0..19
    int row0 = rt * 16;
    int p = lane & 15, kb = (lane >> 4) * 8, quad = (lane >> 4) << 2;
    short8 bfrag = *(const short8*)((const short*)featsB + (row0 + p) * 32 + kb);
    int cbase = seg * SEGW;
    const short* WA = (const short*)W_hoT;
    float racc = 0.f;
    short8 a0n = *(const short8*)(WA + (cbase + p) * 32 + kb);
    short8 a1n = *(const short8*)(WA + (cbase + 16 + p) * 32 + kb);
#pragma unroll 1
    for (int it = 0; it < NIT; ++it) {
        short8 a0 = a0n, a1 = a1n;
        if (it < NIT - 1) {
            int cn = cbase + (it + 1) * 32;
            a0n = *(const short8*)(WA + (cn + p) * 32 + kb);
            a1n = *(const short8*)(WA + (cn + 16 + p) * 32 + kb);
        }
        int c0 = cbase + it * 32;
        f32x4 b40 = *(const f32x4*)(b_ho + c0 + quad);
        f32x4 b41 = *(const f32x4*)(b_ho + c0 + 16 + quad);
        f32x4 lg0 = __builtin_amdgcn_mfma_f32_16x16x32_bf16(a0, bfrag, (f32x4){0.f,0.f,0.f,0.f}, 0, 0, 0);
        f32x4 lg1 = __builtin_amdgcn_mfma_f32_16x16x32_bf16(a1, bfrag, (f32x4){0.f,0.f,0.f,0.f}, 0, 0, 0);
        racc += __expf(lg0[0] + b40[0]) + __expf(lg0[1] + b40[1]) +
                __expf(lg0[2] + b40[2]) + __expf(lg0[3] + b40[3]);
        racc += __expf(lg1[0] + b41[0]) + __expf(lg1[1] + b41[1]) +
                __expf(lg1[2] + b41[2]) + __expf(lg1[3] + b41[3]);
    }
    racc += __shfl_xor(racc, 16, 64);
    racc += __shfl_xor(racc, 32, 64);
    if (lane < 16) stats_part[(row0 + lane) * NSEG + seg] = racc;
}

// Kernel 2b: lse[row] = log(sum of 20 segment partials)
__global__ __launch_bounds__(256) void lse_kernel(const float* __restrict__ stats_part,
                                                  float* __restrict__ lse) {
    int r = blockIdx.x * 256 + threadIdx.x;   // 16 blocks -> 4096
    const float* sp = stats_part + r * NSEG;
    float s = 0.f;
#pragma unroll
    for (int i = 0; i < NSEG; ++i) s += sp[i];
    lse[r] = __logf(s);
}

// Kernel 3: out = logit - lse, recomputed; prefetched afrags; nontemporal f32x4 stores.
__global__ __launch_bounds__(256) void out_kernel(const __hip_bfloat16* __restrict__ featsB,
                                                  const __hip_bfloat16* __restrict__ W_hoT,
                                                  const float* __restrict__ b_ho,
                                                  const float* __restrict__ lse,
                                                  float* __restrict__ out) {
    int wv = threadIdx.x >> 6, lane = threadIdx.x & 63;
    int rt = blockIdx.x * 4 + wv;
    int seg = blockIdx.y;
    int row0 = rt * 16;
    int p = lane & 15, kb = (lane >> 4) * 8, quad = (lane >> 4) << 2;
    short8 bfrag = *(const short8*)((const short*)featsB + (row0 + p) * 32 + kb);
    float ls = lse[row0 + p];
    int cbase = seg * SEGW;
    const short* WA = (const short*)W_hoT;
    float* orow = out + (long)(row0 + p) * V_;
    short8 a0n = *(const short8*)(WA + (cbase + p) * 32 + kb);
    short8 a1n = *(const short8*)(WA + (cbase + 16 + p) * 32 + kb);
#pragma unroll 1
    for (int it = 0; it < NIT; ++it) {
        short8 a0 = a0n, a1 = a1n;
        if (it < NIT - 1) {
            int cn = cbase + (it + 1) * 32;
            a0n = *(const short8*)(WA + (cn + p) * 32 + kb);
            a1n = *(const short8*)(WA + (cn + 16 + p) * 32 + kb);
        }
        int c0 = cbase + it * 32;
        f32x4 b40 = *(const f32x4*)(b_ho + c0 + quad);
        f32x4 b41 = *(const f32x4*)(b_ho + c0 + 16 + quad);
        f32x4 lg0 = __builtin_amdgcn_mfma_f32_16x16x32_bf16(a0, bfrag, (f32x4){0.f,0.f,0.f,0.f}, 0, 0, 0);
        f32x4 lg1 = __builtin_amdgcn_mfma_f32_16x16x32_bf16(a1, bfrag, (f32x4){0.f,0.f,0.f,0.f}, 0, 0, 0);
        f32x4 o0, o1;
#pragma unroll
        for (int q = 0; q < 4; ++q) {
            o0[q] = lg0[q] + b40[q] - ls;
            o1[q] = lg1[q] + b41[q] - ls;
        }
        __builtin_nontemporal_store(o0, (f32x4*)(orow + c0 + quad));
        __builtin_nontemporal_store(o1, (f32x4*)(orow + c0 + 16 + quad));
    }
}

extern "C" void kernel_launch(void* const* d_in, const int* in_sizes, int n_in,
                              void* d_out, int out_size, void* d_ws, size_t ws_size,
                              hipStream_t stream) {
    const int*   ix      = (const int*)d_in[0];
    const float* emb     = (const float*)d_in[1];
    const float* W_lr    = (const float*)d_in[2];
    const float* b_lr    = (const float*)d_in[3];
    const float* W_rl    = (const float*)d_in[4];
    const float* b_rl    = (const float*)d_in[5];
    const float* W_ho    = (const float*)d_in[6];
    const float* b_ho    = (const float*)d_in[7];
    const float* h0      = (const float*)d_in[8];
    const float* mask_lr = (const float*)d_in[9];
    const float* mask_rl = (const float*)d_in[10];
    float* out = (float*)d_out;
    float* ws  = (float*)d_ws;

    float*           xw         = ws;                                   // 131072
    __hip_bfloat16*  featsB     = (__hip_bfloat16*)(ws + 131072);       // 65536
    __hip_bfloat16*  W_hoT      = (__hip_bfloat16*)(ws + 196608);       // 512000
    float*           stats_part = ws + 708608;                          // 81920
    float*           lse        = ws + 790528;                          // 4096

    xw_kernel<<<512, 256, 0, stream>>>(ix, emb, W_lr, b_lr, W_rl, b_rl, xw);
    wt_kernel<<<125, 256, 0, stream>>>(W_ho, W_hoT);
    scan_kernel<<<2, 512, 0, stream>>>(xw, W_lr, W_rl, h0, mask_lr, mask_rl, featsB);
    stats_kernel<<<dim3(64, NSEG), 256, 0, stream>>>(featsB, W_hoT, b_ho, stats_part);
    lse_kernel<<<16, 256, 0, stream>>>(stats_part, lse);
    out_kernel<<<dim3(64, NSEG), 256, 0, stream>>>(featsB, W_hoT, b_ho, lse, out);
}